// Round 1
// baseline (1315.647 us; speedup 1.0000x reference)
//
#include <hip/hip_runtime.h>

#define NFEAT 256
#define EDIM 64

// ---------------- CSR construction ----------------

__global__ void hist_kernel(const int* __restrict__ col, int* __restrict__ deg, int E) {
  int stride = gridDim.x * blockDim.x;
  for (int e = blockIdx.x * blockDim.x + threadIdx.x; e < E; e += stride)
    atomicAdd(&deg[col[e]], 1);
}

// Block-level exclusive scan: 256 threads x 4 items = 1024 items/block.
__global__ void scan1_kernel(const int* __restrict__ deg, int* __restrict__ offs,
                             int* __restrict__ bsum, int N) {
  __shared__ int lds[256];
  int b = blockIdx.x;
  int base = b * 1024;
  int t = threadIdx.x;
  int v[4];
  int s = 0;
#pragma unroll
  for (int j = 0; j < 4; ++j) {
    int i = base + t * 4 + j;
    v[j] = (i < N) ? deg[i] : 0;
    s += v[j];
  }
  lds[t] = s;
  __syncthreads();
  int x = s;
  for (int off = 1; off < 256; off <<= 1) {
    int y = (t >= off) ? lds[t - off] : 0;
    __syncthreads();
    x += y;
    lds[t] = x;
    __syncthreads();
  }
  if (t == 255) bsum[b] = x;
  int excl = x - s;
#pragma unroll
  for (int j = 0; j < 4; ++j) {
    int i = base + t * 4 + j;
    if (i < N) offs[i] = excl;
    excl += v[j];
  }
}

// Single block exclusive scan of block sums (nb <= 256).
__global__ void scan2_kernel(int* __restrict__ bsum, int nb) {
  __shared__ int lds[256];
  int t = threadIdx.x;
  int s = (t < nb) ? bsum[t] : 0;
  lds[t] = s;
  __syncthreads();
  int x = s;
  for (int off = 1; off < 256; off <<= 1) {
    int y = (t >= off) ? lds[t - off] : 0;
    __syncthreads();
    x += y;
    lds[t] = x;
    __syncthreads();
  }
  if (t < nb) bsum[t] = x - s;  // exclusive
}

// Add block offsets, init cursor, compute deg^{-1/2}.
__global__ void finalize_kernel(int* __restrict__ offs, int* __restrict__ cursor,
                                const int* __restrict__ deg, float* __restrict__ dis,
                                const int* __restrict__ bsum, int N) {
  int stride = gridDim.x * blockDim.x;
  for (int i = blockIdx.x * blockDim.x + threadIdx.x; i < N; i += stride) {
    int o = offs[i] + bsum[i >> 10];
    offs[i] = o;
    cursor[i] = o;
    int dg = deg[i];
    dis[i] = (dg > 0) ? rsqrtf((float)dg) : 0.f;
  }
}

__global__ void fill_kernel(const int* __restrict__ row, const int* __restrict__ col,
                            int* __restrict__ cursor, int* __restrict__ csr, int E) {
  int stride = gridDim.x * blockDim.x;
  for (int e = blockIdx.x * blockDim.x + threadIdx.x; e < E; e += stride) {
    int r = row[e];
    int c = col[e];
    int p = atomicAdd(&cursor[c], 1);
    csr[p] = r;
  }
}

// ---------------- Embedding GEMM: x = X @ W^T + b ----------------

__global__ void transposeW_kernel(const float* __restrict__ W, float* __restrict__ Wt) {
  int i = blockIdx.x * blockDim.x + threadIdx.x;
  if (i < EDIM * NFEAT) {
    int d = i >> 8;   // row of W (output dim)
    int k = i & 255;  // col of W (input feat)
    Wt[k * EDIM + d] = W[i];
  }
}

// Block = 256 threads (4 waves). lane = output dim d; each wave handles 8 nodes.
// Block covers 32 nodes. Also initializes out_acc = alpha[0] * x.
__global__ void embed_kernel(const float* __restrict__ X, const float* __restrict__ Wt,
                             const float* __restrict__ bias, const float* __restrict__ alpha,
                             float* __restrict__ x_out, float* __restrict__ out_acc, int N) {
  const int d = threadIdx.x & 63;
  const int wv = threadIdx.x >> 6;
  const int node0 = blockIdx.x * 32 + wv;  // nodes node0 + 4*j, j=0..7
  float acc[8];
#pragma unroll
  for (int j = 0; j < 8; ++j) acc[j] = 0.f;

  for (int k = 0; k < NFEAT; k += 4) {
    float xv[8][4];
#pragma unroll
    for (int j = 0; j < 8; ++j) {
      int node = node0 + 4 * j;
      if (node < N) {
        float4 t = *reinterpret_cast<const float4*>(X + (size_t)node * NFEAT + k);
        xv[j][0] = t.x; xv[j][1] = t.y; xv[j][2] = t.z; xv[j][3] = t.w;
      } else {
        xv[j][0] = xv[j][1] = xv[j][2] = xv[j][3] = 0.f;
      }
    }
#pragma unroll
    for (int kk = 0; kk < 4; ++kk) {
      float w = Wt[(k + kk) * EDIM + d];
#pragma unroll
      for (int j = 0; j < 8; ++j) acc[j] += xv[j][kk] * w;
    }
  }
  float a0 = alpha[0];
  float bb = bias[d];
#pragma unroll
  for (int j = 0; j < 8; ++j) {
    int node = node0 + 4 * j;
    if (node < N) {
      float v = acc[j] + bb;
      x_out[(size_t)node * EDIM + d] = v;
      out_acc[(size_t)node * EDIM + d] = a0 * v;
    }
  }
}

// ---------------- Propagation (gather form, no atomics) ----------------
// Wave per destination node; lane = dim. x_out[c] = dis[c]*sum_e dis[r]*x_in[r].
// Fused: out_acc[c] += alpha[layer+1]*x_out[c].

__global__ void prop_kernel(const float* __restrict__ x_in, float* __restrict__ x_out,
                            float* __restrict__ out_acc, const int* __restrict__ offs,
                            const int* __restrict__ deg, const int* __restrict__ csr,
                            const float* __restrict__ dis, const float* __restrict__ alpha,
                            int layer, int N) {
  int lane = threadIdx.x & 63;
  int wid = (blockIdx.x * blockDim.x + threadIdx.x) >> 6;
  int nw = (gridDim.x * blockDim.x) >> 6;
  float al = alpha[layer + 1];
  for (int c = wid; c < N; c += nw) {
    int start = offs[c];
    int cnt = deg[c];
    float acc = 0.f;
    for (int j = 0; j < cnt; ++j) {
      int r = csr[start + j];
      acc += dis[r] * x_in[(size_t)r * EDIM + lane];
    }
    float val = acc * dis[c];
    size_t o = (size_t)c * EDIM + lane;
    x_out[o] = val;
    out_acc[o] += al * val;
  }
}

// ---------------- Output gather ----------------
// One float4 of output per thread-iteration. Row = [src(64) | dst(64)].

__global__ void gatherout_kernel(const float* __restrict__ oacc, const int* __restrict__ lsrc,
                                 const int* __restrict__ ldst, float* __restrict__ out, int L) {
  long total = (long)L * 32;
  long stride = (long)gridDim.x * blockDim.x;
  for (long i = (long)blockIdx.x * blockDim.x + threadIdx.x; i < total; i += stride) {
    int l = (int)(i >> 5);
    int q = (int)(i & 31);
    int node = (q < 16) ? lsrc[l] : ldst[l];
    int qq = q & 15;
    float4 v = *reinterpret_cast<const float4*>(oacc + (size_t)node * EDIM + qq * 4);
    *reinterpret_cast<float4*>(out + (size_t)l * 128 + q * 4) = v;
  }
}

// ---------------- Launch ----------------

extern "C" void kernel_launch(void* const* d_in, const int* in_sizes, int n_in,
                              void* d_out, int out_size, void* d_ws, size_t ws_size,
                              hipStream_t stream) {
  const float* X = (const float*)d_in[0];
  const float* W = (const float*)d_in[1];
  const float* b = (const float*)d_in[2];
  const float* alpha = (const float*)d_in[3];
  const int* ei = (const int*)d_in[4];
  const int* eli = (const int*)d_in[5];
  int N = in_sizes[0] / NFEAT;
  int E = in_sizes[4] / 2;
  int L = in_sizes[5] / 2;
  const int* rowp = ei;
  const int* colp = ei + E;
  const int* lsrc = eli;
  const int* ldst = eli + L;
  float* out = (float*)d_out;

  char* ws = (char*)d_ws;
  size_t off = 0;
  auto alloc = [&](size_t bytes) -> void* {
    void* p = ws + off;
    off += (bytes + 255) & ~(size_t)255;
    return p;
  };
  int* deg = (int*)alloc((size_t)N * 4);
  int* offs = (int*)alloc((size_t)N * 4);
  int* cursor = (int*)alloc((size_t)N * 4);
  int* bsum = (int*)alloc(1024);
  float* dis = (float*)alloc((size_t)N * 4);
  int* csr = (int*)alloc((size_t)E * 4);
  float* Wt = (float*)alloc((size_t)NFEAT * EDIM * 4);
  float* xa = (float*)alloc((size_t)N * EDIM * 4);
  float* xb = (float*)alloc((size_t)N * EDIM * 4);
  float* oacc = (float*)alloc((size_t)N * EDIM * 4);
  (void)ws_size;
  (void)n_in;
  (void)out_size;

  hipMemsetAsync(deg, 0, (size_t)N * 4, stream);
  hist_kernel<<<2048, 256, 0, stream>>>(colp, deg, E);
  int nb = (N + 1023) / 1024;  // 98 for N=100000; scan2 requires nb <= 256
  scan1_kernel<<<nb, 256, 0, stream>>>(deg, offs, bsum, N);
  scan2_kernel<<<1, 256, 0, stream>>>(bsum, nb);
  finalize_kernel<<<(N + 255) / 256, 256, 0, stream>>>(offs, cursor, deg, dis, bsum, N);
  fill_kernel<<<2048, 256, 0, stream>>>(rowp, colp, cursor, csr, E);
  transposeW_kernel<<<(EDIM * NFEAT + 255) / 256, 256, 0, stream>>>(W, Wt);
  embed_kernel<<<(N + 31) / 32, 256, 0, stream>>>(X, Wt, b, alpha, xa, oacc, N);
  prop_kernel<<<2048, 256, 0, stream>>>(xa, xb, oacc, offs, deg, csr, dis, alpha, 0, N);
  prop_kernel<<<2048, 256, 0, stream>>>(xb, xa, oacc, offs, deg, csr, dis, alpha, 1, N);
  prop_kernel<<<2048, 256, 0, stream>>>(xa, xb, oacc, offs, deg, csr, dis, alpha, 2, N);
  gatherout_kernel<<<4096, 256, 0, stream>>>(oacc, lsrc, ldst, out, L);
}

// Round 2
// 923.331 us; speedup vs baseline: 1.4249x; 1.4249x over previous
//
#include <hip/hip_runtime.h>

#define NFEAT 256
#define EDIM 64

// ---------------- CSR construction ----------------

__global__ void hist_kernel(const int* __restrict__ col, int* __restrict__ deg, int E) {
  int stride = gridDim.x * blockDim.x;
  for (int e = blockIdx.x * blockDim.x + threadIdx.x; e < E; e += stride)
    atomicAdd(&deg[col[e]], 1);
}

// Block-level exclusive scan: 256 threads x 4 items = 1024 items/block.
__global__ void scan1_kernel(const int* __restrict__ deg, int* __restrict__ offs,
                             int* __restrict__ bsum, int N) {
  __shared__ int lds[256];
  int b = blockIdx.x;
  int base = b * 1024;
  int t = threadIdx.x;
  int v[4];
  int s = 0;
#pragma unroll
  for (int j = 0; j < 4; ++j) {
    int i = base + t * 4 + j;
    v[j] = (i < N) ? deg[i] : 0;
    s += v[j];
  }
  lds[t] = s;
  __syncthreads();
  int x = s;
  for (int off = 1; off < 256; off <<= 1) {
    int y = (t >= off) ? lds[t - off] : 0;
    __syncthreads();
    x += y;
    lds[t] = x;
    __syncthreads();
  }
  if (t == 255) bsum[b] = x;
  int excl = x - s;
#pragma unroll
  for (int j = 0; j < 4; ++j) {
    int i = base + t * 4 + j;
    if (i < N) offs[i] = excl;
    excl += v[j];
  }
}

// Single block exclusive scan of block sums (nb <= 256).
__global__ void scan2_kernel(int* __restrict__ bsum, int nb) {
  __shared__ int lds[256];
  int t = threadIdx.x;
  int s = (t < nb) ? bsum[t] : 0;
  lds[t] = s;
  __syncthreads();
  int x = s;
  for (int off = 1; off < 256; off <<= 1) {
    int y = (t >= off) ? lds[t - off] : 0;
    __syncthreads();
    x += y;
    lds[t] = x;
    __syncthreads();
  }
  if (t < nb) bsum[t] = x - s;  // exclusive
}

// Add block offsets, init cursor, compute deg^{-1/2}.
__global__ void finalize_kernel(int* __restrict__ offs, int* __restrict__ cursor,
                                const int* __restrict__ deg, float* __restrict__ dis,
                                const int* __restrict__ bsum, int N) {
  int stride = gridDim.x * blockDim.x;
  for (int i = blockIdx.x * blockDim.x + threadIdx.x; i < N; i += stride) {
    int o = offs[i] + bsum[i >> 10];
    offs[i] = o;
    cursor[i] = o;
    int dg = deg[i];
    dis[i] = (dg > 0) ? rsqrtf((float)dg) : 0.f;
  }
}

__global__ void fill_kernel(const int* __restrict__ row, const int* __restrict__ col,
                            int* __restrict__ cursor, int* __restrict__ csr, int E) {
  int stride = gridDim.x * blockDim.x;
  for (int e = blockIdx.x * blockDim.x + threadIdx.x; e < E; e += stride) {
    int r = row[e];
    int c = col[e];
    int p = atomicAdd(&cursor[c], 1);
    csr[p] = r;
  }
}

// ---------------- Embedding GEMM: x = X @ W^T + b ----------------

__global__ void transposeW_kernel(const float* __restrict__ W, float* __restrict__ Wt) {
  int i = blockIdx.x * blockDim.x + threadIdx.x;
  if (i < EDIM * NFEAT) {
    int d = i >> 8;   // row of W (output dim)
    int k = i & 255;  // col of W (input feat)
    Wt[k * EDIM + d] = W[i];
  }
}

// One wave per block. lane = node; all 64 output dims live in registers.
// X loads: per-lane float4 from the lane's own row (L1-friendly, each line
// consumed over 4 consecutive k4 steps). W loads: wave-uniform -> scalar
// cache (s_load), leaving VALU free for the 256 FMAs per k4 step.
__global__ void __launch_bounds__(64) embed_kernel(
    const float* __restrict__ X, const float* __restrict__ Wt,
    const float* __restrict__ bias, const float* __restrict__ alpha,
    float* __restrict__ x_out, float* __restrict__ out_acc, int N) {
  const int lane = threadIdx.x;           // 0..63
  const int node = blockIdx.x * 64 + lane;
  const bool valid = node < N;
  const int nclamp = valid ? node : (N - 1);
  const float4* __restrict__ Xrow = reinterpret_cast<const float4*>(X + (size_t)nclamp * NFEAT);

  float acc[EDIM];
#pragma unroll
  for (int d = 0; d < EDIM; ++d) acc[d] = 0.f;

  auto fma_block = [&](float4 xv, int k4) {
    const float* __restrict__ wrow = Wt + (size_t)k4 * (4 * EDIM);
#pragma unroll
    for (int kk = 0; kk < 4; ++kk) {
      float xk = (kk == 0) ? xv.x : (kk == 1) ? xv.y : (kk == 2) ? xv.z : xv.w;
#pragma unroll
      for (int d = 0; d < EDIM; ++d)
        acc[d] = fmaf(xk, wrow[kk * EDIM + d], acc[d]);
    }
  };

  float4 xv = Xrow[0];
#pragma unroll 1
  for (int k4 = 0; k4 < NFEAT / 4 - 1; ++k4) {
    float4 xn = Xrow[k4 + 1];  // prefetch next 16B while FMAs run
    fma_block(xv, k4);
    xv = xn;
  }
  fma_block(xv, NFEAT / 4 - 1);

  if (valid) {
    float a0 = alpha[0];
    float* __restrict__ xo = x_out + (size_t)node * EDIM;
    float* __restrict__ oa = out_acc + (size_t)node * EDIM;
#pragma unroll
    for (int d4 = 0; d4 < EDIM / 4; ++d4) {
      float4 v;
      v.x = acc[d4 * 4 + 0] + bias[d4 * 4 + 0];
      v.y = acc[d4 * 4 + 1] + bias[d4 * 4 + 1];
      v.z = acc[d4 * 4 + 2] + bias[d4 * 4 + 2];
      v.w = acc[d4 * 4 + 3] + bias[d4 * 4 + 3];
      *reinterpret_cast<float4*>(xo + d4 * 4) = v;
      float4 o;
      o.x = a0 * v.x; o.y = a0 * v.y; o.z = a0 * v.z; o.w = a0 * v.w;
      *reinterpret_cast<float4*>(oa + d4 * 4) = o;
    }
  }
}

// ---------------- Propagation (gather form, no atomics) ----------------
// Wave per destination node; lane = dim. x_out[c] = dis[c]*sum_e dis[r]*x_in[r].
// Fused: out_acc[c] += alpha[layer+1]*x_out[c].

__global__ void prop_kernel(const float* __restrict__ x_in, float* __restrict__ x_out,
                            float* __restrict__ out_acc, const int* __restrict__ offs,
                            const int* __restrict__ deg, const int* __restrict__ csr,
                            const float* __restrict__ dis, const float* __restrict__ alpha,
                            int layer, int N) {
  int lane = threadIdx.x & 63;
  int wid = (blockIdx.x * blockDim.x + threadIdx.x) >> 6;
  int nw = (gridDim.x * blockDim.x) >> 6;
  float al = alpha[layer + 1];
  for (int c = wid; c < N; c += nw) {
    int start = offs[c];
    int cnt = deg[c];
    float acc = 0.f;
    for (int j = 0; j < cnt; ++j) {
      int r = csr[start + j];
      acc += dis[r] * x_in[(size_t)r * EDIM + lane];
    }
    float val = acc * dis[c];
    size_t o = (size_t)c * EDIM + lane;
    x_out[o] = val;
    out_acc[o] += al * val;
  }
}

// ---------------- Output gather ----------------
// One float4 of output per thread-iteration. Row = [src(64) | dst(64)].

__global__ void gatherout_kernel(const float* __restrict__ oacc, const int* __restrict__ lsrc,
                                 const int* __restrict__ ldst, float* __restrict__ out, int L) {
  long total = (long)L * 32;
  long stride = (long)gridDim.x * blockDim.x;
  for (long i = (long)blockIdx.x * blockDim.x + threadIdx.x; i < total; i += stride) {
    int l = (int)(i >> 5);
    int q = (int)(i & 31);
    int node = (q < 16) ? lsrc[l] : ldst[l];
    int qq = q & 15;
    float4 v = *reinterpret_cast<const float4*>(oacc + (size_t)node * EDIM + qq * 4);
    *reinterpret_cast<float4*>(out + (size_t)l * 128 + q * 4) = v;
  }
}

// ---------------- Launch ----------------

extern "C" void kernel_launch(void* const* d_in, const int* in_sizes, int n_in,
                              void* d_out, int out_size, void* d_ws, size_t ws_size,
                              hipStream_t stream) {
  const float* X = (const float*)d_in[0];
  const float* W = (const float*)d_in[1];
  const float* b = (const float*)d_in[2];
  const float* alpha = (const float*)d_in[3];
  const int* ei = (const int*)d_in[4];
  const int* eli = (const int*)d_in[5];
  int N = in_sizes[0] / NFEAT;
  int E = in_sizes[4] / 2;
  int L = in_sizes[5] / 2;
  const int* rowp = ei;
  const int* colp = ei + E;
  const int* lsrc = eli;
  const int* ldst = eli + L;
  float* out = (float*)d_out;

  char* ws = (char*)d_ws;
  size_t off = 0;
  auto alloc = [&](size_t bytes) -> void* {
    void* p = ws + off;
    off += (bytes + 255) & ~(size_t)255;
    return p;
  };
  int* deg = (int*)alloc((size_t)N * 4);
  int* offs = (int*)alloc((size_t)N * 4);
  int* cursor = (int*)alloc((size_t)N * 4);
  int* bsum = (int*)alloc(1024);
  float* dis = (float*)alloc((size_t)N * 4);
  int* csr = (int*)alloc((size_t)E * 4);
  float* Wt = (float*)alloc((size_t)NFEAT * EDIM * 4);
  float* xa = (float*)alloc((size_t)N * EDIM * 4);
  float* xb = (float*)alloc((size_t)N * EDIM * 4);
  float* oacc = (float*)alloc((size_t)N * EDIM * 4);
  (void)ws_size;
  (void)n_in;
  (void)out_size;

  hipMemsetAsync(deg, 0, (size_t)N * 4, stream);
  hist_kernel<<<2048, 256, 0, stream>>>(colp, deg, E);
  int nb = (N + 1023) / 1024;  // 98 for N=100000; scan2 requires nb <= 256
  scan1_kernel<<<nb, 256, 0, stream>>>(deg, offs, bsum, N);
  scan2_kernel<<<1, 256, 0, stream>>>(bsum, nb);
  finalize_kernel<<<(N + 255) / 256, 256, 0, stream>>>(offs, cursor, deg, dis, bsum, N);
  fill_kernel<<<2048, 256, 0, stream>>>(rowp, colp, cursor, csr, E);
  transposeW_kernel<<<(EDIM * NFEAT + 255) / 256, 256, 0, stream>>>(W, Wt);
  embed_kernel<<<(N + 63) / 64, 64, 0, stream>>>(X, Wt, b, alpha, xa, oacc, N);
  prop_kernel<<<2048, 256, 0, stream>>>(xa, xb, oacc, offs, deg, csr, dis, alpha, 0, N);
  prop_kernel<<<2048, 256, 0, stream>>>(xb, xa, oacc, offs, deg, csr, dis, alpha, 1, N);
  prop_kernel<<<2048, 256, 0, stream>>>(xa, xb, oacc, offs, deg, csr, dis, alpha, 2, N);
  gatherout_kernel<<<4096, 256, 0, stream>>>(oacc, lsrc, ldst, out, L);
}

// Round 4
// 656.689 us; speedup vs baseline: 2.0035x; 1.4060x over previous
//
#include <hip/hip_runtime.h>

#define NFEAT 256
#define EDIM 64

typedef float f4_t __attribute__((ext_vector_type(4)));

// ---------------- CSR construction ----------------

__global__ void hist_kernel(const int* __restrict__ col, int* __restrict__ deg, int E) {
  int stride = gridDim.x * blockDim.x;
  for (int e = blockIdx.x * blockDim.x + threadIdx.x; e < E; e += stride)
    atomicAdd(&deg[col[e]], 1);
}

// Block-level exclusive scan: 256 threads x 4 items = 1024 items/block.
__global__ void scan1_kernel(const int* __restrict__ deg, int* __restrict__ offs,
                             int* __restrict__ bsum, int N) {
  __shared__ int lds[256];
  int b = blockIdx.x;
  int base = b * 1024;
  int t = threadIdx.x;
  int v[4];
  int s = 0;
#pragma unroll
  for (int j = 0; j < 4; ++j) {
    int i = base + t * 4 + j;
    v[j] = (i < N) ? deg[i] : 0;
    s += v[j];
  }
  lds[t] = s;
  __syncthreads();
  int x = s;
  for (int off = 1; off < 256; off <<= 1) {
    int y = (t >= off) ? lds[t - off] : 0;
    __syncthreads();
    x += y;
    lds[t] = x;
    __syncthreads();
  }
  if (t == 255) bsum[b] = x;
  int excl = x - s;
#pragma unroll
  for (int j = 0; j < 4; ++j) {
    int i = base + t * 4 + j;
    if (i < N) offs[i] = excl;
    excl += v[j];
  }
}

// Single block exclusive scan of block sums (nb <= 256).
__global__ void scan2_kernel(int* __restrict__ bsum, int nb) {
  __shared__ int lds[256];
  int t = threadIdx.x;
  int s = (t < nb) ? bsum[t] : 0;
  lds[t] = s;
  __syncthreads();
  int x = s;
  for (int off = 1; off < 256; off <<= 1) {
    int y = (t >= off) ? lds[t - off] : 0;
    __syncthreads();
    x += y;
    lds[t] = x;
    __syncthreads();
  }
  if (t < nb) bsum[t] = x - s;  // exclusive
}

// Add block offsets, init cursor, compute deg^{-1/2}.
__global__ void finalize_kernel(int* __restrict__ offs, int* __restrict__ cursor,
                                const int* __restrict__ deg, float* __restrict__ dis,
                                const int* __restrict__ bsum, int N) {
  int stride = gridDim.x * blockDim.x;
  for (int i = blockIdx.x * blockDim.x + threadIdx.x; i < N; i += stride) {
    int o = offs[i] + bsum[i >> 10];
    offs[i] = o;
    cursor[i] = o;
    int dg = deg[i];
    dis[i] = (dg > 0) ? rsqrtf((float)dg) : 0.f;
  }
}

// Fill CSR with (src, dis[src]) pairs so prop needs no random dis gather.
__global__ void fill_kernel(const int* __restrict__ row, const int* __restrict__ col,
                            int* __restrict__ cursor, int2* __restrict__ csr,
                            const float* __restrict__ dis, int E) {
  int stride = gridDim.x * blockDim.x;
  for (int e = blockIdx.x * blockDim.x + threadIdx.x; e < E; e += stride) {
    int r = row[e];
    int c = col[e];
    int p = atomicAdd(&cursor[c], 1);
    csr[p] = make_int2(r, __float_as_int(dis[r]));
  }
}

// ---------------- Embedding GEMM: x = X @ W^T + b ----------------

__global__ void transposeW_kernel(const float* __restrict__ W, float* __restrict__ Wt) {
  int i = blockIdx.x * blockDim.x + threadIdx.x;
  if (i < EDIM * NFEAT) {
    int d = i >> 8;   // row of W (output dim)
    int k = i & 255;  // col of W (input feat)
    Wt[k * EDIM + d] = W[i];
  }
}

// Thread = node; all 64 output dims live in registers. X loads: per-lane
// float4 from the lane's own row. W loads: wave-uniform -> scalar cache.
__global__ void __launch_bounds__(256) embed_kernel(
    const float* __restrict__ X, const float* __restrict__ Wt,
    const float* __restrict__ bias, float* __restrict__ x_out, int N) {
  const int node = blockIdx.x * 256 + threadIdx.x;
  const bool valid = node < N;
  const int nclamp = valid ? node : (N - 1);
  const float4* __restrict__ Xrow = reinterpret_cast<const float4*>(X + (size_t)nclamp * NFEAT);

  float acc[EDIM];
#pragma unroll
  for (int d = 0; d < EDIM; ++d) acc[d] = 0.f;

  auto fma_block = [&](float4 xv, int k4) {
    const float* __restrict__ wrow = Wt + (size_t)k4 * (4 * EDIM);
#pragma unroll
    for (int kk = 0; kk < 4; ++kk) {
      float xk = (kk == 0) ? xv.x : (kk == 1) ? xv.y : (kk == 2) ? xv.z : xv.w;
#pragma unroll
      for (int d = 0; d < EDIM; ++d)
        acc[d] = fmaf(xk, wrow[kk * EDIM + d], acc[d]);
    }
  };

  float4 xv = Xrow[0];
#pragma unroll 1
  for (int k4 = 0; k4 < NFEAT / 4 - 1; ++k4) {
    float4 xn = Xrow[k4 + 1];  // prefetch next 16B while FMAs run
    fma_block(xv, k4);
    xv = xn;
  }
  fma_block(xv, NFEAT / 4 - 1);

  if (valid) {
    float* __restrict__ xo = x_out + (size_t)node * EDIM;
#pragma unroll
    for (int d4 = 0; d4 < EDIM / 4; ++d4) {
      float4 v;
      v.x = acc[d4 * 4 + 0] + bias[d4 * 4 + 0];
      v.y = acc[d4 * 4 + 1] + bias[d4 * 4 + 1];
      v.z = acc[d4 * 4 + 2] + bias[d4 * 4 + 2];
      v.w = acc[d4 * 4 + 3] + bias[d4 * 4 + 3];
      *reinterpret_cast<float4*>(xo + d4 * 4) = v;
    }
  }
}

// ---------------- Propagation (gather form, no atomics) ----------------
// Wave per destination node; lane = dim. x_out[c] = dis[c]*sum_e dis[r]*x_in[r].
// Unroll-4: keep 4 independent row-gathers in flight to cover L2/L3 latency.
// layer==0 also initializes out_acc = alpha[0]*x_in[c] + alpha[1]*val.
// last layer skips the dead x_out store.

__global__ void prop_kernel(const float* __restrict__ x_in, float* __restrict__ x_out,
                            float* __restrict__ out_acc, const int* __restrict__ offs,
                            const int* __restrict__ deg, const int2* __restrict__ csr,
                            const float* __restrict__ dis, const float* __restrict__ alpha,
                            int layer, int last, int N) {
  int lane = threadIdx.x & 63;
  int wid = (blockIdx.x * blockDim.x + threadIdx.x) >> 6;
  int nw = (gridDim.x * blockDim.x) >> 6;
  float al = alpha[layer + 1];
  float a0 = alpha[0];
  for (int c = wid; c < N; c += nw) {
    int start = offs[c];
    int cnt = deg[c];
    float acc = 0.f;
    int j = 0;
    for (; j + 4 <= cnt; j += 4) {
      int2 e0 = csr[start + j + 0];
      int2 e1 = csr[start + j + 1];
      int2 e2 = csr[start + j + 2];
      int2 e3 = csr[start + j + 3];
      float v0 = x_in[(size_t)e0.x * EDIM + lane];
      float v1 = x_in[(size_t)e1.x * EDIM + lane];
      float v2 = x_in[(size_t)e2.x * EDIM + lane];
      float v3 = x_in[(size_t)e3.x * EDIM + lane];
      acc = fmaf(__int_as_float(e0.y), v0, acc);
      acc = fmaf(__int_as_float(e1.y), v1, acc);
      acc = fmaf(__int_as_float(e2.y), v2, acc);
      acc = fmaf(__int_as_float(e3.y), v3, acc);
    }
    for (; j < cnt; ++j) {
      int2 e = csr[start + j];
      acc = fmaf(__int_as_float(e.y), x_in[(size_t)e.x * EDIM + lane], acc);
    }
    float val = acc * dis[c];
    size_t o = (size_t)c * EDIM + lane;
    if (!last) x_out[o] = val;
    if (layer == 0) {
      out_acc[o] = fmaf(a0, x_in[o], al * val);
    } else {
      out_acc[o] += al * val;
    }
  }
}

// ---------------- Output gather ----------------
// One float4 of output per thread-iteration. Row = [src(64) | dst(64)].
// Nontemporal stores: stream the 512MB output past L2 so oacc stays resident.

__global__ void gatherout_kernel(const float* __restrict__ oacc, const int* __restrict__ lsrc,
                                 const int* __restrict__ ldst, float* __restrict__ out, int L) {
  long total = (long)L * 32;
  long stride = (long)gridDim.x * blockDim.x;
  for (long i = (long)blockIdx.x * blockDim.x + threadIdx.x; i < total; i += stride) {
    int l = (int)(i >> 5);
    int q = (int)(i & 31);
    int node = (q < 16) ? lsrc[l] : ldst[l];
    int qq = q & 15;
    f4_t v = *reinterpret_cast<const f4_t*>(oacc + (size_t)node * EDIM + qq * 4);
    __builtin_nontemporal_store(v, reinterpret_cast<f4_t*>(out + (size_t)l * 128 + q * 4));
  }
}

// ---------------- Launch ----------------

extern "C" void kernel_launch(void* const* d_in, const int* in_sizes, int n_in,
                              void* d_out, int out_size, void* d_ws, size_t ws_size,
                              hipStream_t stream) {
  const float* X = (const float*)d_in[0];
  const float* W = (const float*)d_in[1];
  const float* b = (const float*)d_in[2];
  const float* alpha = (const float*)d_in[3];
  const int* ei = (const int*)d_in[4];
  const int* eli = (const int*)d_in[5];
  int N = in_sizes[0] / NFEAT;
  int E = in_sizes[4] / 2;
  int L = in_sizes[5] / 2;
  const int* rowp = ei;
  const int* colp = ei + E;
  const int* lsrc = eli;
  const int* ldst = eli + L;
  float* out = (float*)d_out;

  char* ws = (char*)d_ws;
  size_t off = 0;
  auto alloc = [&](size_t bytes) -> void* {
    void* p = ws + off;
    off += (bytes + 255) & ~(size_t)255;
    return p;
  };
  int* deg = (int*)alloc((size_t)N * 4);
  int* offs = (int*)alloc((size_t)N * 4);
  int* cursor = (int*)alloc((size_t)N * 4);
  int* bsum = (int*)alloc(1024);
  float* dis = (float*)alloc((size_t)N * 4);
  int2* csr = (int2*)alloc((size_t)E * 8);
  float* Wt = (float*)alloc((size_t)NFEAT * EDIM * 4);
  float* xa = (float*)alloc((size_t)N * EDIM * 4);
  float* xb = (float*)alloc((size_t)N * EDIM * 4);
  float* oacc = (float*)alloc((size_t)N * EDIM * 4);
  (void)ws_size;
  (void)n_in;
  (void)out_size;

  (void)hipMemsetAsync(deg, 0, (size_t)N * 4, stream);
  hist_kernel<<<2048, 256, 0, stream>>>(colp, deg, E);
  int nb = (N + 1023) / 1024;  // 98 for N=100000; scan2 requires nb <= 256
  scan1_kernel<<<nb, 256, 0, stream>>>(deg, offs, bsum, N);
  scan2_kernel<<<1, 256, 0, stream>>>(bsum, nb);
  finalize_kernel<<<(N + 255) / 256, 256, 0, stream>>>(offs, cursor, deg, dis, bsum, N);
  fill_kernel<<<2048, 256, 0, stream>>>(rowp, colp, cursor, csr, dis, E);
  transposeW_kernel<<<(EDIM * NFEAT + 255) / 256, 256, 0, stream>>>(W, Wt);
  embed_kernel<<<(N + 255) / 256, 256, 0, stream>>>(X, Wt, b, xa, N);
  prop_kernel<<<2048, 256, 0, stream>>>(xa, xb, oacc, offs, deg, csr, dis, alpha, 0, 0, N);
  prop_kernel<<<2048, 256, 0, stream>>>(xb, xa, oacc, offs, deg, csr, dis, alpha, 1, 0, N);
  prop_kernel<<<2048, 256, 0, stream>>>(xa, xb, oacc, offs, deg, csr, dis, alpha, 2, 1, N);
  gatherout_kernel<<<4096, 256, 0, stream>>>(oacc, lsrc, ldst, out, L);
}

// Round 5
// 636.076 us; speedup vs baseline: 2.0684x; 1.0324x over previous
//
#include <hip/hip_runtime.h>
#include <hip/hip_fp16.h>

#define NFEAT 256
#define EDIM 64

typedef float f4_t __attribute__((ext_vector_type(4)));

// ---------------- CSR construction ----------------

__global__ void hist_kernel(const int* __restrict__ col, int* __restrict__ deg, int E) {
  int stride = gridDim.x * blockDim.x;
  for (int e = blockIdx.x * blockDim.x + threadIdx.x; e < E; e += stride)
    atomicAdd(&deg[col[e]], 1);
}

// Block-level exclusive scan: 256 threads x 4 items = 1024 items/block.
__global__ void scan1_kernel(const int* __restrict__ deg, int* __restrict__ offs,
                             int* __restrict__ bsum, int N) {
  __shared__ int lds[256];
  int b = blockIdx.x;
  int base = b * 1024;
  int t = threadIdx.x;
  int v[4];
  int s = 0;
#pragma unroll
  for (int j = 0; j < 4; ++j) {
    int i = base + t * 4 + j;
    v[j] = (i < N) ? deg[i] : 0;
    s += v[j];
  }
  lds[t] = s;
  __syncthreads();
  int x = s;
  for (int off = 1; off < 256; off <<= 1) {
    int y = (t >= off) ? lds[t - off] : 0;
    __syncthreads();
    x += y;
    lds[t] = x;
    __syncthreads();
  }
  if (t == 255) bsum[b] = x;
  int excl = x - s;
#pragma unroll
  for (int j = 0; j < 4; ++j) {
    int i = base + t * 4 + j;
    if (i < N) offs[i] = excl;
    excl += v[j];
  }
}

// Single block exclusive scan of block sums (nb <= 256).
__global__ void scan2_kernel(int* __restrict__ bsum, int nb) {
  __shared__ int lds[256];
  int t = threadIdx.x;
  int s = (t < nb) ? bsum[t] : 0;
  lds[t] = s;
  __syncthreads();
  int x = s;
  for (int off = 1; off < 256; off <<= 1) {
    int y = (t >= off) ? lds[t - off] : 0;
    __syncthreads();
    x += y;
    lds[t] = x;
    __syncthreads();
  }
  if (t < nb) bsum[t] = x - s;  // exclusive
}

// Add block offsets, init cursor, compute deg^{-1/2}.
__global__ void finalize_kernel(int* __restrict__ offs, int* __restrict__ cursor,
                                const int* __restrict__ deg, float* __restrict__ dis,
                                const int* __restrict__ bsum, int N) {
  int stride = gridDim.x * blockDim.x;
  for (int i = blockIdx.x * blockDim.x + threadIdx.x; i < N; i += stride) {
    int o = offs[i] + bsum[i >> 10];
    offs[i] = o;
    cursor[i] = o;
    int dg = deg[i];
    dis[i] = (dg > 0) ? rsqrtf((float)dg) : 0.f;
  }
}

// Fill CSR with (src, dis[src]) pairs so prop needs no random dis gather.
__global__ void fill_kernel(const int* __restrict__ row, const int* __restrict__ col,
                            int* __restrict__ cursor, int2* __restrict__ csr,
                            const float* __restrict__ dis, int E) {
  int stride = gridDim.x * blockDim.x;
  for (int e = blockIdx.x * blockDim.x + threadIdx.x; e < E; e += stride) {
    int r = row[e];
    int c = col[e];
    int p = atomicAdd(&cursor[c], 1);
    csr[p] = make_int2(r, __float_as_int(dis[r]));
  }
}

// ---------------- Embedding GEMM: x = X @ W^T + b (fp16 out) ----------------

__global__ void transposeW_kernel(const float* __restrict__ W, float* __restrict__ Wt) {
  int i = blockIdx.x * blockDim.x + threadIdx.x;
  if (i < EDIM * NFEAT) {
    int d = i >> 8;   // row of W (output dim)
    int k = i & 255;  // col of W (input feat)
    Wt[k * EDIM + d] = W[i];
  }
}

// Thread = node; all 64 output dims live in registers. X loads: per-lane
// float4 from the lane's own row. W loads: wave-uniform -> scalar cache.
__global__ void __launch_bounds__(256) embed_kernel(
    const float* __restrict__ X, const float* __restrict__ Wt,
    const float* __restrict__ bias, __half* __restrict__ x_out, int N) {
  const int node = blockIdx.x * 256 + threadIdx.x;
  const bool valid = node < N;
  const int nclamp = valid ? node : (N - 1);
  const float4* __restrict__ Xrow = reinterpret_cast<const float4*>(X + (size_t)nclamp * NFEAT);

  float acc[EDIM];
#pragma unroll
  for (int d = 0; d < EDIM; ++d) acc[d] = 0.f;

  auto fma_block = [&](float4 xv, int k4) {
    const float* __restrict__ wrow = Wt + (size_t)k4 * (4 * EDIM);
#pragma unroll
    for (int kk = 0; kk < 4; ++kk) {
      float xk = (kk == 0) ? xv.x : (kk == 1) ? xv.y : (kk == 2) ? xv.z : xv.w;
#pragma unroll
      for (int d = 0; d < EDIM; ++d)
        acc[d] = fmaf(xk, wrow[kk * EDIM + d], acc[d]);
    }
  };

  float4 xv = Xrow[0];
#pragma unroll 1
  for (int k4 = 0; k4 < NFEAT / 4 - 1; ++k4) {
    float4 xn = Xrow[k4 + 1];  // prefetch next 16B while FMAs run
    fma_block(xv, k4);
    xv = xn;
  }
  fma_block(xv, NFEAT / 4 - 1);

  if (valid) {
    float4* __restrict__ dst = reinterpret_cast<float4*>(x_out + (size_t)node * EDIM);
#pragma unroll
    for (int q = 0; q < 8; ++q) {
      float4 v;
      float* vp = &v.x;
#pragma unroll
      for (int h = 0; h < 4; ++h) {
        int d = q * 8 + h * 2;
        __half2 hh = __floats2half2_rn(acc[d] + bias[d], acc[d + 1] + bias[d + 1]);
        vp[h] = __uint_as_float(*reinterpret_cast<unsigned int*>(&hh));
      }
      dst[q] = v;
    }
  }
}

// ---------------- Propagation (gather form, no atomics) ----------------
// Wave per destination node. Wave splits into two 32-lane halves; each half
// processes a contiguous slice of the dst's edge list with half2 (dim-pair)
// loads: one load instruction covers 2 edges x 128B. Unroll-4 => 8 gathers
// in flight per wave. f32 accumulate; cross-half combine via shfl_xor(32).
// layer==0 initializes out_acc = alpha[0]*x_in[c] + alpha[1]*val.
// last layer skips the dead x_out store.

__global__ void prop_kernel(const __half* __restrict__ x_in, __half* __restrict__ x_out,
                            float* __restrict__ out_acc, const int* __restrict__ offs,
                            const int* __restrict__ deg, const int2* __restrict__ csr,
                            const float* __restrict__ dis, const float* __restrict__ alpha,
                            int layer, int last, int N) {
  const int lane = threadIdx.x & 63;
  const int hf = lane >> 5;    // 0 or 1: which edge-slice
  const int sub = lane & 31;   // dim pair index: dims 2*sub, 2*sub+1
  int wid = (blockIdx.x * blockDim.x + threadIdx.x) >> 6;
  int nw = (gridDim.x * blockDim.x) >> 6;
  float al = alpha[layer + 1];
  float a0 = alpha[0];
  const int2 z2 = make_int2(0, 0);
  for (int c = wid; c < N; c += nw) {
    int start = offs[c];
    int cnt = deg[c];
    int cntA = (cnt + 1) >> 1;
    int myCnt = hf ? (cnt - cntA) : cntA;
    int myStart = start + hf * cntA;
    float ax = 0.f, ay = 0.f;
    int j = 0;
    for (; j + 4 <= cntA; j += 4) {
      int2 e0 = (j + 0 < myCnt) ? csr[myStart + j + 0] : z2;
      int2 e1 = (j + 1 < myCnt) ? csr[myStart + j + 1] : z2;
      int2 e2 = (j + 2 < myCnt) ? csr[myStart + j + 2] : z2;
      int2 e3 = (j + 3 < myCnt) ? csr[myStart + j + 3] : z2;
      float2 v0 = __half22float2(*((const __half2*)(x_in + ((size_t)e0.x * EDIM)) + sub));
      float2 v1 = __half22float2(*((const __half2*)(x_in + ((size_t)e1.x * EDIM)) + sub));
      float2 v2 = __half22float2(*((const __half2*)(x_in + ((size_t)e2.x * EDIM)) + sub));
      float2 v3 = __half22float2(*((const __half2*)(x_in + ((size_t)e3.x * EDIM)) + sub));
      float w0 = __int_as_float(e0.y), w1 = __int_as_float(e1.y);
      float w2 = __int_as_float(e2.y), w3 = __int_as_float(e3.y);
      ax = fmaf(w0, v0.x, ax); ay = fmaf(w0, v0.y, ay);
      ax = fmaf(w1, v1.x, ax); ay = fmaf(w1, v1.y, ay);
      ax = fmaf(w2, v2.x, ax); ay = fmaf(w2, v2.y, ay);
      ax = fmaf(w3, v3.x, ax); ay = fmaf(w3, v3.y, ay);
    }
    for (; j < cntA; ++j) {
      int2 e = (j < myCnt) ? csr[myStart + j] : z2;
      float2 v = __half22float2(*((const __half2*)(x_in + ((size_t)e.x * EDIM)) + sub));
      float w = __int_as_float(e.y);
      ax = fmaf(w, v.x, ax); ay = fmaf(w, v.y, ay);
    }
    ax += __shfl_xor(ax, 32);
    ay += __shfl_xor(ay, 32);
    if (hf == 0) {
      float dc = dis[c];
      float vx = ax * dc, vy = ay * dc;
      size_t base = (size_t)c * EDIM + sub * 2;
      if (!last) *reinterpret_cast<__half2*>(x_out + base) = __floats2half2_rn(vx, vy);
      float2 o;
      if (layer == 0) {
        float2 xf = __half22float2(*reinterpret_cast<const __half2*>(x_in + base));
        o.x = fmaf(a0, xf.x, al * vx);
        o.y = fmaf(a0, xf.y, al * vy);
      } else {
        const float2 prev = *reinterpret_cast<const float2*>(out_acc + base);
        o.x = fmaf(al, vx, prev.x);
        o.y = fmaf(al, vy, prev.y);
      }
      *reinterpret_cast<float2*>(out_acc + base) = o;
    }
  }
}

// ---------------- Output gather ----------------
// One float4 of output per thread-iteration. Row = [src(64) | dst(64)].
// Nontemporal stores: stream the 512MB output past L2 so oacc stays resident.

__global__ void gatherout_kernel(const float* __restrict__ oacc, const int* __restrict__ lsrc,
                                 const int* __restrict__ ldst, float* __restrict__ out, int L) {
  long total = (long)L * 32;
  long stride = (long)gridDim.x * blockDim.x;
  for (long i = (long)blockIdx.x * blockDim.x + threadIdx.x; i < total; i += stride) {
    int l = (int)(i >> 5);
    int q = (int)(i & 31);
    int node = (q < 16) ? lsrc[l] : ldst[l];
    int qq = q & 15;
    f4_t v = *reinterpret_cast<const f4_t*>(oacc + (size_t)node * EDIM + qq * 4);
    __builtin_nontemporal_store(v, reinterpret_cast<f4_t*>(out + (size_t)l * 128 + q * 4));
  }
}

// ---------------- Launch ----------------

extern "C" void kernel_launch(void* const* d_in, const int* in_sizes, int n_in,
                              void* d_out, int out_size, void* d_ws, size_t ws_size,
                              hipStream_t stream) {
  const float* X = (const float*)d_in[0];
  const float* W = (const float*)d_in[1];
  const float* b = (const float*)d_in[2];
  const float* alpha = (const float*)d_in[3];
  const int* ei = (const int*)d_in[4];
  const int* eli = (const int*)d_in[5];
  int N = in_sizes[0] / NFEAT;
  int E = in_sizes[4] / 2;
  int L = in_sizes[5] / 2;
  const int* rowp = ei;
  const int* colp = ei + E;
  const int* lsrc = eli;
  const int* ldst = eli + L;
  float* out = (float*)d_out;

  char* ws = (char*)d_ws;
  size_t off = 0;
  auto alloc = [&](size_t bytes) -> void* {
    void* p = ws + off;
    off += (bytes + 255) & ~(size_t)255;
    return p;
  };
  int* deg = (int*)alloc((size_t)N * 4);
  int* offs = (int*)alloc((size_t)N * 4);
  int* cursor = (int*)alloc((size_t)N * 4);
  int* bsum = (int*)alloc(1024);
  float* dis = (float*)alloc((size_t)N * 4);
  int2* csr = (int2*)alloc((size_t)(E + 16) * 8);
  float* Wt = (float*)alloc((size_t)NFEAT * EDIM * 4);
  __half* xa = (__half*)alloc((size_t)N * EDIM * 2);
  __half* xb = (__half*)alloc((size_t)N * EDIM * 2);
  float* oacc = (float*)alloc((size_t)N * EDIM * 4);
  (void)ws_size;
  (void)n_in;
  (void)out_size;

  (void)hipMemsetAsync(deg, 0, (size_t)N * 4, stream);
  hist_kernel<<<2048, 256, 0, stream>>>(colp, deg, E);
  int nb = (N + 1023) / 1024;  // 98 for N=100000; scan2 requires nb <= 256
  scan1_kernel<<<nb, 256, 0, stream>>>(deg, offs, bsum, N);
  scan2_kernel<<<1, 256, 0, stream>>>(bsum, nb);
  finalize_kernel<<<(N + 255) / 256, 256, 0, stream>>>(offs, cursor, deg, dis, bsum, N);
  fill_kernel<<<2048, 256, 0, stream>>>(rowp, colp, cursor, csr, dis, E);
  transposeW_kernel<<<(EDIM * NFEAT + 255) / 256, 256, 0, stream>>>(W, Wt);
  embed_kernel<<<(N + 255) / 256, 256, 0, stream>>>(X, Wt, b, xa, N);
  prop_kernel<<<2048, 256, 0, stream>>>(xa, xb, oacc, offs, deg, csr, dis, alpha, 0, 0, N);
  prop_kernel<<<2048, 256, 0, stream>>>(xb, xa, oacc, offs, deg, csr, dis, alpha, 1, 0, N);
  prop_kernel<<<2048, 256, 0, stream>>>(xa, xb, oacc, offs, deg, csr, dis, alpha, 2, 1, N);
  gatherout_kernel<<<4096, 256, 0, stream>>>(oacc, lsrc, ldst, out, L);
}

// Round 6
// 574.214 us; speedup vs baseline: 2.2912x; 1.1077x over previous
//
#include <hip/hip_runtime.h>
#include <hip/hip_fp16.h>

#define NFEAT 256
#define EDIM 64

typedef float f4_t __attribute__((ext_vector_type(4)));
typedef _Float16 f16x8 __attribute__((ext_vector_type(8)));
typedef float f32x4 __attribute__((ext_vector_type(4)));

// ---------------- CSR construction ----------------

__global__ void hist_kernel(const int* __restrict__ col, int* __restrict__ deg, int E) {
  int stride = gridDim.x * blockDim.x;
  for (int e = blockIdx.x * blockDim.x + threadIdx.x; e < E; e += stride)
    atomicAdd(&deg[col[e]], 1);
}

// Block-level exclusive scan: 256 threads x 4 items = 1024 items/block.
__global__ void scan1_kernel(const int* __restrict__ deg, int* __restrict__ offs,
                             int* __restrict__ bsum, int N) {
  __shared__ int lds[256];
  int b = blockIdx.x;
  int base = b * 1024;
  int t = threadIdx.x;
  int v[4];
  int s = 0;
#pragma unroll
  for (int j = 0; j < 4; ++j) {
    int i = base + t * 4 + j;
    v[j] = (i < N) ? deg[i] : 0;
    s += v[j];
  }
  lds[t] = s;
  __syncthreads();
  int x = s;
  for (int off = 1; off < 256; off <<= 1) {
    int y = (t >= off) ? lds[t - off] : 0;
    __syncthreads();
    x += y;
    lds[t] = x;
    __syncthreads();
  }
  if (t == 255) bsum[b] = x;
  int excl = x - s;
#pragma unroll
  for (int j = 0; j < 4; ++j) {
    int i = base + t * 4 + j;
    if (i < N) offs[i] = excl;
    excl += v[j];
  }
}

// Single block exclusive scan of block sums (nb <= 256).
__global__ void scan2_kernel(int* __restrict__ bsum, int nb) {
  __shared__ int lds[256];
  int t = threadIdx.x;
  int s = (t < nb) ? bsum[t] : 0;
  lds[t] = s;
  __syncthreads();
  int x = s;
  for (int off = 1; off < 256; off <<= 1) {
    int y = (t >= off) ? lds[t - off] : 0;
    __syncthreads();
    x += y;
    lds[t] = x;
    __syncthreads();
  }
  if (t < nb) bsum[t] = x - s;  // exclusive
}

// Add block offsets, init cursor, compute deg^{-1/2}.
__global__ void finalize_kernel(int* __restrict__ offs, int* __restrict__ cursor,
                                const int* __restrict__ deg, float* __restrict__ dis,
                                const int* __restrict__ bsum, int N) {
  int stride = gridDim.x * blockDim.x;
  for (int i = blockIdx.x * blockDim.x + threadIdx.x; i < N; i += stride) {
    int o = offs[i] + bsum[i >> 10];
    offs[i] = o;
    cursor[i] = o;
    int dg = deg[i];
    dis[i] = (dg > 0) ? rsqrtf((float)dg) : 0.f;
  }
}

// Fill CSR with (src, dis[src]) pairs so prop needs no random dis gather.
__global__ void fill_kernel(const int* __restrict__ row, const int* __restrict__ col,
                            int* __restrict__ cursor, int2* __restrict__ csr,
                            const float* __restrict__ dis, int E) {
  int stride = gridDim.x * blockDim.x;
  for (int e = blockIdx.x * blockDim.x + threadIdx.x; e < E; e += stride) {
    int r = row[e];
    int c = col[e];
    int p = atomicAdd(&cursor[c], 1);
    csr[p] = make_int2(r, __float_as_int(dis[r]));
  }
}

// ---------------- Embedding GEMM via MFMA: x = fp16(X) @ fp16(W)^T + b ------
// Block = 256 threads (4 waves), 64 nodes/block. Stage X-tile (64x256) and all
// of W (64x256) as fp16 in LDS (padded stride 264 to balance banks). Each wave
// computes 16 nodes x 64 dims with 4 accumulators over 8 k-steps of 32.
// A frag: lane holds 8 contiguous k of node row (l&15), k-group (l>>4).
// B frag: lane holds 8 contiguous k of W row dim (l&15 within tile).
// C layout: col = lane&15, row = (lane>>4)*4 + reg  [m89-verified].
#define LDS_STRIDE 264

__global__ void __launch_bounds__(256) embed_kernel(
    const float* __restrict__ X, const float* __restrict__ W,
    const float* __restrict__ bias, __half* __restrict__ x_out, int N) {
  __shared__ _Float16 Xl[64 * LDS_STRIDE];
  __shared__ _Float16 Wl[64 * LDS_STRIDE];
  const int t = threadIdx.x;
  const int base = blockIdx.x * 64;

  // Stage W and X tile: 16 passes x 256 threads x float4.
#pragma unroll 4
  for (int p = 0; p < 16; ++p) {
    int flat = p * 256 + t;
    int row = flat >> 6;        // 0..63
    int col4 = flat & 63;       // float4 index within row of 256
    // W row = output dim; layout already [dim][k].
    float4 wv = *reinterpret_cast<const float4*>(W + (size_t)row * NFEAT + col4 * 4);
    __half2 w01 = __floats2half2_rn(wv.x, wv.y);
    __half2 w23 = __floats2half2_rn(wv.z, wv.w);
    uint2 wp = make_uint2(*reinterpret_cast<unsigned int*>(&w01),
                          *reinterpret_cast<unsigned int*>(&w23));
    *reinterpret_cast<uint2*>(&Wl[row * LDS_STRIDE + col4 * 4]) = wp;

    int xrow = base + row;
    int xr = (xrow < N) ? xrow : (N - 1);
    float4 xv = *reinterpret_cast<const float4*>(X + (size_t)xr * NFEAT + col4 * 4);
    __half2 x01 = __floats2half2_rn(xv.x, xv.y);
    __half2 x23 = __floats2half2_rn(xv.z, xv.w);
    uint2 xp = make_uint2(*reinterpret_cast<unsigned int*>(&x01),
                          *reinterpret_cast<unsigned int*>(&x23));
    *reinterpret_cast<uint2*>(&Xl[row * LDS_STRIDE + col4 * 4]) = xp;
  }
  __syncthreads();

  const int lane = t & 63;
  const int w = t >> 6;        // wave id: nodes base + w*16 .. +15
  const int r = lane & 15;
  const int g = lane >> 4;

  f32x4 acc[4];
#pragma unroll
  for (int n = 0; n < 4; ++n) acc[n] = (f32x4){0.f, 0.f, 0.f, 0.f};

#pragma unroll
  for (int s = 0; s < 8; ++s) {
    f16x8 a = *reinterpret_cast<const f16x8*>(&Xl[(w * 16 + r) * LDS_STRIDE + s * 32 + 8 * g]);
#pragma unroll
    for (int n = 0; n < 4; ++n) {
      f16x8 bfr = *reinterpret_cast<const f16x8*>(&Wl[(n * 16 + r) * LDS_STRIDE + s * 32 + 8 * g]);
      acc[n] = __builtin_amdgcn_mfma_f32_16x16x32_f16(a, bfr, acc[n], 0, 0, 0);
    }
  }

  // Epilogue: node = base + w*16 + g*4 + reg, dim = n*16 + r.
  float bv[4];
#pragma unroll
  for (int n = 0; n < 4; ++n) bv[n] = bias[n * 16 + r];
#pragma unroll
  for (int reg = 0; reg < 4; ++reg) {
    int node = base + w * 16 + g * 4 + reg;
    if (node < N) {
#pragma unroll
      for (int n = 0; n < 4; ++n) {
        float val = acc[n][reg] + bv[n];
        x_out[(size_t)node * EDIM + n * 16 + r] = __float2half(val);
      }
    }
  }
}

// ---------------- Propagation (gather form, no atomics) ----------------
// Wave per destination node. Wave splits into two 32-lane halves; each half
// processes a contiguous slice of the dst's edge list with half2 (dim-pair)
// loads. Unroll-4 => 8 gathers in flight per wave. f32 accumulate;
// cross-half combine via shfl_xor(32).
// layer==0 initializes out_acc = alpha[0]*x_in[c] + alpha[1]*val.
// last layer skips the dead x_out store.

__global__ void prop_kernel(const __half* __restrict__ x_in, __half* __restrict__ x_out,
                            float* __restrict__ out_acc, const int* __restrict__ offs,
                            const int* __restrict__ deg, const int2* __restrict__ csr,
                            const float* __restrict__ dis, const float* __restrict__ alpha,
                            int layer, int last, int N) {
  const int lane = threadIdx.x & 63;
  const int hf = lane >> 5;    // 0 or 1: which edge-slice
  const int sub = lane & 31;   // dim pair index: dims 2*sub, 2*sub+1
  int wid = (blockIdx.x * blockDim.x + threadIdx.x) >> 6;
  int nw = (gridDim.x * blockDim.x) >> 6;
  float al = alpha[layer + 1];
  float a0 = alpha[0];
  const int2 z2 = make_int2(0, 0);
  for (int c = wid; c < N; c += nw) {
    int start = offs[c];
    int cnt = deg[c];
    int cntA = (cnt + 1) >> 1;
    int myCnt = hf ? (cnt - cntA) : cntA;
    int myStart = start + hf * cntA;
    float ax = 0.f, ay = 0.f;
    int j = 0;
    for (; j + 4 <= cntA; j += 4) {
      int2 e0 = (j + 0 < myCnt) ? csr[myStart + j + 0] : z2;
      int2 e1 = (j + 1 < myCnt) ? csr[myStart + j + 1] : z2;
      int2 e2 = (j + 2 < myCnt) ? csr[myStart + j + 2] : z2;
      int2 e3 = (j + 3 < myCnt) ? csr[myStart + j + 3] : z2;
      float2 v0 = __half22float2(*((const __half2*)(x_in + ((size_t)e0.x * EDIM)) + sub));
      float2 v1 = __half22float2(*((const __half2*)(x_in + ((size_t)e1.x * EDIM)) + sub));
      float2 v2 = __half22float2(*((const __half2*)(x_in + ((size_t)e2.x * EDIM)) + sub));
      float2 v3 = __half22float2(*((const __half2*)(x_in + ((size_t)e3.x * EDIM)) + sub));
      float w0 = __int_as_float(e0.y), w1 = __int_as_float(e1.y);
      float w2 = __int_as_float(e2.y), w3 = __int_as_float(e3.y);
      ax = fmaf(w0, v0.x, ax); ay = fmaf(w0, v0.y, ay);
      ax = fmaf(w1, v1.x, ax); ay = fmaf(w1, v1.y, ay);
      ax = fmaf(w2, v2.x, ax); ay = fmaf(w2, v2.y, ay);
      ax = fmaf(w3, v3.x, ax); ay = fmaf(w3, v3.y, ay);
    }
    for (; j < cntA; ++j) {
      int2 e = (j < myCnt) ? csr[myStart + j] : z2;
      float2 v = __half22float2(*((const __half2*)(x_in + ((size_t)e.x * EDIM)) + sub));
      float w = __int_as_float(e.y);
      ax = fmaf(w, v.x, ax); ay = fmaf(w, v.y, ay);
    }
    ax += __shfl_xor(ax, 32);
    ay += __shfl_xor(ay, 32);
    if (hf == 0) {
      float dc = dis[c];
      float vx = ax * dc, vy = ay * dc;
      size_t base = (size_t)c * EDIM + sub * 2;
      if (!last) *reinterpret_cast<__half2*>(x_out + base) = __floats2half2_rn(vx, vy);
      float2 o;
      if (layer == 0) {
        float2 xf = __half22float2(*reinterpret_cast<const __half2*>(x_in + base));
        o.x = fmaf(a0, xf.x, al * vx);
        o.y = fmaf(a0, xf.y, al * vy);
      } else {
        const float2 prev = *reinterpret_cast<const float2*>(out_acc + base);
        o.x = fmaf(al, vx, prev.x);
        o.y = fmaf(al, vy, prev.y);
      }
      *reinterpret_cast<float2*>(out_acc + base) = o;
    }
  }
}

// ---------------- Output gather ----------------
// One float4 of output per thread-iteration. Row = [src(64) | dst(64)].
// Nontemporal stores: stream the 512MB output past L2 so oacc stays resident.

__global__ void gatherout_kernel(const float* __restrict__ oacc, const int* __restrict__ lsrc,
                                 const int* __restrict__ ldst, float* __restrict__ out, int L) {
  long total = (long)L * 32;
  long stride = (long)gridDim.x * blockDim.x;
  for (long i = (long)blockIdx.x * blockDim.x + threadIdx.x; i < total; i += stride) {
    int l = (int)(i >> 5);
    int q = (int)(i & 31);
    int node = (q < 16) ? lsrc[l] : ldst[l];
    int qq = q & 15;
    f4_t v = *reinterpret_cast<const f4_t*>(oacc + (size_t)node * EDIM + qq * 4);
    __builtin_nontemporal_store(v, reinterpret_cast<f4_t*>(out + (size_t)l * 128 + q * 4));
  }
}

// ---------------- Launch ----------------

extern "C" void kernel_launch(void* const* d_in, const int* in_sizes, int n_in,
                              void* d_out, int out_size, void* d_ws, size_t ws_size,
                              hipStream_t stream) {
  const float* X = (const float*)d_in[0];
  const float* W = (const float*)d_in[1];
  const float* b = (const float*)d_in[2];
  const float* alpha = (const float*)d_in[3];
  const int* ei = (const int*)d_in[4];
  const int* eli = (const int*)d_in[5];
  int N = in_sizes[0] / NFEAT;
  int E = in_sizes[4] / 2;
  int L = in_sizes[5] / 2;
  const int* rowp = ei;
  const int* colp = ei + E;
  const int* lsrc = eli;
  const int* ldst = eli + L;
  float* out = (float*)d_out;

  char* ws = (char*)d_ws;
  size_t off = 0;
  auto alloc = [&](size_t bytes) -> void* {
    void* p = ws + off;
    off += (bytes + 255) & ~(size_t)255;
    return p;
  };
  int* deg = (int*)alloc((size_t)N * 4);
  int* offs = (int*)alloc((size_t)N * 4);
  int* cursor = (int*)alloc((size_t)N * 4);
  int* bsum = (int*)alloc(1024);
  float* dis = (float*)alloc((size_t)N * 4);
  int2* csr = (int2*)alloc((size_t)(E + 16) * 8);
  __half* xa = (__half*)alloc((size_t)N * EDIM * 2);
  __half* xb = (__half*)alloc((size_t)N * EDIM * 2);
  float* oacc = (float*)alloc((size_t)N * EDIM * 4);
  (void)ws_size;
  (void)n_in;
  (void)out_size;

  (void)hipMemsetAsync(deg, 0, (size_t)N * 4, stream);
  hist_kernel<<<2048, 256, 0, stream>>>(colp, deg, E);
  int nb = (N + 1023) / 1024;  // 98 for N=100000; scan2 requires nb <= 256
  scan1_kernel<<<nb, 256, 0, stream>>>(deg, offs, bsum, N);
  scan2_kernel<<<1, 256, 0, stream>>>(bsum, nb);
  finalize_kernel<<<(N + 255) / 256, 256, 0, stream>>>(offs, cursor, deg, dis, bsum, N);
  fill_kernel<<<2048, 256, 0, stream>>>(rowp, colp, cursor, csr, dis, E);
  embed_kernel<<<(N + 63) / 64, 256, 0, stream>>>(X, W, b, xa, N);
  prop_kernel<<<2048, 256, 0, stream>>>(xa, xb, oacc, offs, deg, csr, dis, alpha, 0, 0, N);
  prop_kernel<<<2048, 256, 0, stream>>>(xb, xa, oacc, offs, deg, csr, dis, alpha, 1, 0, N);
  prop_kernel<<<2048, 256, 0, stream>>>(xa, xb, oacc, offs, deg, csr, dis, alpha, 2, 1, N);
  gatherout_kernel<<<4096, 256, 0, stream>>>(oacc, lsrc, ldst, out, L);
}

// Round 7
// 545.714 us; speedup vs baseline: 2.4109x; 1.0522x over previous
//
#include <hip/hip_runtime.h>
#include <hip/hip_fp16.h>

#define NFEAT 256
#define EDIM 64

typedef float f4_t __attribute__((ext_vector_type(4)));
typedef _Float16 f16x8 __attribute__((ext_vector_type(8)));
typedef float f32x4 __attribute__((ext_vector_type(4)));

// ---------------- CSR construction ----------------

__global__ void hist_kernel(const int* __restrict__ col, int* __restrict__ deg, int E) {
  int stride = gridDim.x * blockDim.x;
  for (int e = blockIdx.x * blockDim.x + threadIdx.x; e < E; e += stride)
    atomicAdd(&deg[col[e]], 1);
}

// Block-level exclusive scan: 256 threads x 4 items = 1024 items/block.
__global__ void scan1_kernel(const int* __restrict__ deg, int* __restrict__ offs,
                             int* __restrict__ bsum, int N) {
  __shared__ int lds[256];
  int b = blockIdx.x;
  int base = b * 1024;
  int t = threadIdx.x;
  int v[4];
  int s = 0;
#pragma unroll
  for (int j = 0; j < 4; ++j) {
    int i = base + t * 4 + j;
    v[j] = (i < N) ? deg[i] : 0;
    s += v[j];
  }
  lds[t] = s;
  __syncthreads();
  int x = s;
  for (int off = 1; off < 256; off <<= 1) {
    int y = (t >= off) ? lds[t - off] : 0;
    __syncthreads();
    x += y;
    lds[t] = x;
    __syncthreads();
  }
  if (t == 255) bsum[b] = x;
  int excl = x - s;
#pragma unroll
  for (int j = 0; j < 4; ++j) {
    int i = base + t * 4 + j;
    if (i < N) offs[i] = excl;
    excl += v[j];
  }
}

// Single block exclusive scan of block sums (nb <= 256).
__global__ void scan2_kernel(int* __restrict__ bsum, int nb) {
  __shared__ int lds[256];
  int t = threadIdx.x;
  int s = (t < nb) ? bsum[t] : 0;
  lds[t] = s;
  __syncthreads();
  int x = s;
  for (int off = 1; off < 256; off <<= 1) {
    int y = (t >= off) ? lds[t - off] : 0;
    __syncthreads();
    x += y;
    lds[t] = x;
    __syncthreads();
  }
  if (t < nb) bsum[t] = x - s;  // exclusive
}

// Add block offsets, init cursor, compute deg^{-1/2}.
__global__ void finalize_kernel(int* __restrict__ offs, int* __restrict__ cursor,
                                const int* __restrict__ deg, float* __restrict__ dis,
                                const int* __restrict__ bsum, int N) {
  int stride = gridDim.x * blockDim.x;
  for (int i = blockIdx.x * blockDim.x + threadIdx.x; i < N; i += stride) {
    int o = offs[i] + bsum[i >> 10];
    offs[i] = o;
    cursor[i] = o;
    int dg = deg[i];
    dis[i] = (dg > 0) ? rsqrtf((float)dg) : 0.f;
  }
}

// Fill CSR with (src, dis[src]) pairs so prop needs no random dis gather.
__global__ void fill_kernel(const int* __restrict__ row, const int* __restrict__ col,
                            int* __restrict__ cursor, int2* __restrict__ csr,
                            const float* __restrict__ dis, int E) {
  int stride = gridDim.x * blockDim.x;
  for (int e = blockIdx.x * blockDim.x + threadIdx.x; e < E; e += stride) {
    int r = row[e];
    int c = col[e];
    int p = atomicAdd(&cursor[c], 1);
    csr[p] = make_int2(r, __float_as_int(dis[r]));
  }
}

// ---------------- Embedding GEMM via MFMA: x = fp16(X) @ fp16(W)^T + b ------
// Block = 256 threads (4 waves), 64 nodes/block. Stage X-tile (64x256) and all
// of W (64x256) as fp16 in LDS (padded stride 264 to balance banks). Each wave
// computes 16 nodes x 64 dims with 4 accumulators over 8 k-steps of 32.
// C layout: col = lane&15, row = (lane>>4)*4 + reg  [m89-verified].
#define LDS_STRIDE 264

__global__ void __launch_bounds__(256) embed_kernel(
    const float* __restrict__ X, const float* __restrict__ W,
    const float* __restrict__ bias, __half* __restrict__ x_out, int N) {
  __shared__ _Float16 Xl[64 * LDS_STRIDE];
  __shared__ _Float16 Wl[64 * LDS_STRIDE];
  const int t = threadIdx.x;
  const int base = blockIdx.x * 64;

  // Stage W and X tile: 16 passes x 256 threads x float4.
#pragma unroll 4
  for (int p = 0; p < 16; ++p) {
    int flat = p * 256 + t;
    int row = flat >> 6;        // 0..63
    int col4 = flat & 63;       // float4 index within row of 256
    float4 wv = *reinterpret_cast<const float4*>(W + (size_t)row * NFEAT + col4 * 4);
    __half2 w01 = __floats2half2_rn(wv.x, wv.y);
    __half2 w23 = __floats2half2_rn(wv.z, wv.w);
    uint2 wp = make_uint2(*reinterpret_cast<unsigned int*>(&w01),
                          *reinterpret_cast<unsigned int*>(&w23));
    *reinterpret_cast<uint2*>(&Wl[row * LDS_STRIDE + col4 * 4]) = wp;

    int xrow = base + row;
    int xr = (xrow < N) ? xrow : (N - 1);
    float4 xv = *reinterpret_cast<const float4*>(X + (size_t)xr * NFEAT + col4 * 4);
    __half2 x01 = __floats2half2_rn(xv.x, xv.y);
    __half2 x23 = __floats2half2_rn(xv.z, xv.w);
    uint2 xp = make_uint2(*reinterpret_cast<unsigned int*>(&x01),
                          *reinterpret_cast<unsigned int*>(&x23));
    *reinterpret_cast<uint2*>(&Xl[row * LDS_STRIDE + col4 * 4]) = xp;
  }
  __syncthreads();

  const int lane = t & 63;
  const int w = t >> 6;        // wave id: nodes base + w*16 .. +15
  const int r = lane & 15;
  const int g = lane >> 4;

  f32x4 acc[4];
#pragma unroll
  for (int n = 0; n < 4; ++n) acc[n] = (f32x4){0.f, 0.f, 0.f, 0.f};

#pragma unroll
  for (int s = 0; s < 8; ++s) {
    f16x8 a = *reinterpret_cast<const f16x8*>(&Xl[(w * 16 + r) * LDS_STRIDE + s * 32 + 8 * g]);
#pragma unroll
    for (int n = 0; n < 4; ++n) {
      f16x8 bfr = *reinterpret_cast<const f16x8*>(&Wl[(n * 16 + r) * LDS_STRIDE + s * 32 + 8 * g]);
      acc[n] = __builtin_amdgcn_mfma_f32_16x16x32_f16(a, bfr, acc[n], 0, 0, 0);
    }
  }

  // Epilogue: node = base + w*16 + g*4 + reg, dim = n*16 + r.
  float bv[4];
#pragma unroll
  for (int n = 0; n < 4; ++n) bv[n] = bias[n * 16 + r];
#pragma unroll
  for (int reg = 0; reg < 4; ++reg) {
    int node = base + w * 16 + g * 4 + reg;
    if (node < N) {
#pragma unroll
      for (int n = 0; n < 4; ++n) {
        float val = acc[n][reg] + bv[n];
        x_out[(size_t)node * EDIM + n * 16 + r] = __float2half(val);
      }
    }
  }
}

// ---------------- Propagation (gather form, no atomics) ----------------
// Wave per destination node; two 32-lane halves each process a contiguous
// slice of the dst's edge list with half2 (dim-pair) loads. Unroll-4 => 8
// gathers in flight per wave. f32 accumulate; cross-half shfl_xor(32).
// out_acc is fp16: layer==0 initializes it to alpha[0]*x_in + alpha[1]*val;
// later layers RMW in fp16. Last layer skips the dead x_out store.

__global__ void prop_kernel(const __half* __restrict__ x_in, __half* __restrict__ x_out,
                            __half* __restrict__ out_acc, const int* __restrict__ offs,
                            const int* __restrict__ deg, const int2* __restrict__ csr,
                            const float* __restrict__ dis, const float* __restrict__ alpha,
                            int layer, int last, int N) {
  const int lane = threadIdx.x & 63;
  const int hf = lane >> 5;    // 0 or 1: which edge-slice
  const int sub = lane & 31;   // dim pair index: dims 2*sub, 2*sub+1
  int wid = (blockIdx.x * blockDim.x + threadIdx.x) >> 6;
  int nw = (gridDim.x * blockDim.x) >> 6;
  float al = alpha[layer + 1];
  float a0 = alpha[0];
  const int2 z2 = make_int2(0, 0);
  for (int c = wid; c < N; c += nw) {
    int start = offs[c];
    int cnt = deg[c];
    int cntA = (cnt + 1) >> 1;
    int myCnt = hf ? (cnt - cntA) : cntA;
    int myStart = start + hf * cntA;
    float ax = 0.f, ay = 0.f;
    int j = 0;
    for (; j + 4 <= cntA; j += 4) {
      int2 e0 = (j + 0 < myCnt) ? csr[myStart + j + 0] : z2;
      int2 e1 = (j + 1 < myCnt) ? csr[myStart + j + 1] : z2;
      int2 e2 = (j + 2 < myCnt) ? csr[myStart + j + 2] : z2;
      int2 e3 = (j + 3 < myCnt) ? csr[myStart + j + 3] : z2;
      float2 v0 = __half22float2(*((const __half2*)(x_in + ((size_t)e0.x * EDIM)) + sub));
      float2 v1 = __half22float2(*((const __half2*)(x_in + ((size_t)e1.x * EDIM)) + sub));
      float2 v2 = __half22float2(*((const __half2*)(x_in + ((size_t)e2.x * EDIM)) + sub));
      float2 v3 = __half22float2(*((const __half2*)(x_in + ((size_t)e3.x * EDIM)) + sub));
      float w0 = __int_as_float(e0.y), w1 = __int_as_float(e1.y);
      float w2 = __int_as_float(e2.y), w3 = __int_as_float(e3.y);
      ax = fmaf(w0, v0.x, ax); ay = fmaf(w0, v0.y, ay);
      ax = fmaf(w1, v1.x, ax); ay = fmaf(w1, v1.y, ay);
      ax = fmaf(w2, v2.x, ax); ay = fmaf(w2, v2.y, ay);
      ax = fmaf(w3, v3.x, ax); ay = fmaf(w3, v3.y, ay);
    }
    for (; j < cntA; ++j) {
      int2 e = (j < myCnt) ? csr[myStart + j] : z2;
      float2 v = __half22float2(*((const __half2*)(x_in + ((size_t)e.x * EDIM)) + sub));
      float w = __int_as_float(e.y);
      ax = fmaf(w, v.x, ax); ay = fmaf(w, v.y, ay);
    }
    ax += __shfl_xor(ax, 32);
    ay += __shfl_xor(ay, 32);
    if (hf == 0) {
      float dc = dis[c];
      float vx = ax * dc, vy = ay * dc;
      size_t base = (size_t)c * EDIM + sub * 2;
      if (!last) *reinterpret_cast<__half2*>(x_out + base) = __floats2half2_rn(vx, vy);
      float2 o;
      if (layer == 0) {
        float2 xf = __half22float2(*reinterpret_cast<const __half2*>(x_in + base));
        o.x = fmaf(a0, xf.x, al * vx);
        o.y = fmaf(a0, xf.y, al * vy);
      } else {
        float2 prev = __half22float2(*reinterpret_cast<const __half2*>(out_acc + base));
        o.x = fmaf(al, vx, prev.x);
        o.y = fmaf(al, vy, prev.y);
      }
      *reinterpret_cast<__half2*>(out_acc + base) = __floats2half2_rn(o.x, o.y);
    }
  }
}

// ---------------- Output gather ----------------
// One float4 of output per thread-iteration. Row = [src(64) | dst(64)].
// oacc is fp16: per float4 of output read one uint2 (4 halfs), convert, and
// nontemporal-store f32. Pure 32-bit arithmetic in the hot loop.

__global__ void gatherout_kernel(const __half* __restrict__ oacc, const int* __restrict__ lsrc,
                                 const int* __restrict__ ldst, float* __restrict__ out, int L) {
  int total = L * 32;
  int stride = gridDim.x * blockDim.x;
  for (int i = blockIdx.x * blockDim.x + threadIdx.x; i < total; i += stride) {
    int l = i >> 5;
    int q = i & 31;
    int node = (q < 16) ? lsrc[l] : ldst[l];
    int qq = q & 15;
    uint2 h = *reinterpret_cast<const uint2*>(oacc + (size_t)node * EDIM + qq * 4);
    float2 lo = __half22float2(*reinterpret_cast<const __half2*>(&h.x));
    float2 hi = __half22float2(*reinterpret_cast<const __half2*>(&h.y));
    f4_t v = {lo.x, lo.y, hi.x, hi.y};
    __builtin_nontemporal_store(v, reinterpret_cast<f4_t*>(out + (size_t)l * 128 + q * 4));
  }
}

// ---------------- Launch ----------------

extern "C" void kernel_launch(void* const* d_in, const int* in_sizes, int n_in,
                              void* d_out, int out_size, void* d_ws, size_t ws_size,
                              hipStream_t stream) {
  const float* X = (const float*)d_in[0];
  const float* W = (const float*)d_in[1];
  const float* b = (const float*)d_in[2];
  const float* alpha = (const float*)d_in[3];
  const int* ei = (const int*)d_in[4];
  const int* eli = (const int*)d_in[5];
  int N = in_sizes[0] / NFEAT;
  int E = in_sizes[4] / 2;
  int L = in_sizes[5] / 2;
  const int* rowp = ei;
  const int* colp = ei + E;
  const int* lsrc = eli;
  const int* ldst = eli + L;
  float* out = (float*)d_out;

  char* ws = (char*)d_ws;
  size_t off = 0;
  auto alloc = [&](size_t bytes) -> void* {
    void* p = ws + off;
    off += (bytes + 255) & ~(size_t)255;
    return p;
  };
  int* deg = (int*)alloc((size_t)N * 4);
  int* offs = (int*)alloc((size_t)N * 4);
  int* cursor = (int*)alloc((size_t)N * 4);
  int* bsum = (int*)alloc(1024);
  float* dis = (float*)alloc((size_t)N * 4);
  int2* csr = (int2*)alloc((size_t)(E + 16) * 8);
  __half* xa = (__half*)alloc((size_t)N * EDIM * 2);
  __half* xb = (__half*)alloc((size_t)N * EDIM * 2);
  __half* oacc = (__half*)alloc((size_t)N * EDIM * 2);
  (void)ws_size;
  (void)n_in;
  (void)out_size;

  (void)hipMemsetAsync(deg, 0, (size_t)N * 4, stream);
  hist_kernel<<<2048, 256, 0, stream>>>(colp, deg, E);
  int nb = (N + 1023) / 1024;  // 98 for N=100000; scan2 requires nb <= 256
  scan1_kernel<<<nb, 256, 0, stream>>>(deg, offs, bsum, N);
  scan2_kernel<<<1, 256, 0, stream>>>(bsum, nb);
  finalize_kernel<<<(N + 255) / 256, 256, 0, stream>>>(offs, cursor, deg, dis, bsum, N);
  fill_kernel<<<2048, 256, 0, stream>>>(rowp, colp, cursor, csr, dis, E);
  embed_kernel<<<(N + 63) / 64, 256, 0, stream>>>(X, W, b, xa, N);
  prop_kernel<<<2048, 256, 0, stream>>>(xa, xb, oacc, offs, deg, csr, dis, alpha, 0, 0, N);
  prop_kernel<<<2048, 256, 0, stream>>>(xb, xa, oacc, offs, deg, csr, dis, alpha, 1, 0, N);
  prop_kernel<<<2048, 256, 0, stream>>>(xa, xb, oacc, offs, deg, csr, dis, alpha, 2, 1, N);
  gatherout_kernel<<<4096, 256, 0, stream>>>(oacc, lsrc, ldst, out, L);
}

// Round 8
// 543.084 us; speedup vs baseline: 2.4225x; 1.0048x over previous
//
#include <hip/hip_runtime.h>
#include <hip/hip_fp16.h>

#define NFEAT 256
#define EDIM 64

typedef float f4_t __attribute__((ext_vector_type(4)));
typedef _Float16 f16x8 __attribute__((ext_vector_type(8)));
typedef float f32x4 __attribute__((ext_vector_type(4)));

// ---------------- CSR construction ----------------

__global__ void hist_kernel(const int* __restrict__ col, int* __restrict__ deg, int E) {
  int stride = gridDim.x * blockDim.x;
  for (int e = blockIdx.x * blockDim.x + threadIdx.x; e < E; e += stride)
    atomicAdd(&deg[col[e]], 1);
}

// Block-level exclusive scan: 256 threads x 4 items = 1024 items/block.
__global__ void scan1_kernel(const int* __restrict__ deg, int* __restrict__ offs,
                             int* __restrict__ bsum, int N) {
  __shared__ int lds[256];
  int b = blockIdx.x;
  int base = b * 1024;
  int t = threadIdx.x;
  int v[4];
  int s = 0;
#pragma unroll
  for (int j = 0; j < 4; ++j) {
    int i = base + t * 4 + j;
    v[j] = (i < N) ? deg[i] : 0;
    s += v[j];
  }
  lds[t] = s;
  __syncthreads();
  int x = s;
  for (int off = 1; off < 256; off <<= 1) {
    int y = (t >= off) ? lds[t - off] : 0;
    __syncthreads();
    x += y;
    lds[t] = x;
    __syncthreads();
  }
  if (t == 255) bsum[b] = x;
  int excl = x - s;
#pragma unroll
  for (int j = 0; j < 4; ++j) {
    int i = base + t * 4 + j;
    if (i < N) offs[i] = excl;
    excl += v[j];
  }
}

// Single block exclusive scan of block sums (nb <= 256).
__global__ void scan2_kernel(int* __restrict__ bsum, int nb) {
  __shared__ int lds[256];
  int t = threadIdx.x;
  int s = (t < nb) ? bsum[t] : 0;
  lds[t] = s;
  __syncthreads();
  int x = s;
  for (int off = 1; off < 256; off <<= 1) {
    int y = (t >= off) ? lds[t - off] : 0;
    __syncthreads();
    x += y;
    lds[t] = x;
    __syncthreads();
  }
  if (t < nb) bsum[t] = x - s;  // exclusive
}

// Add block offsets, init cursor, compute deg^{-1/2}.
__global__ void finalize_kernel(int* __restrict__ offs, int* __restrict__ cursor,
                                const int* __restrict__ deg, float* __restrict__ dis,
                                const int* __restrict__ bsum, int N) {
  int stride = gridDim.x * blockDim.x;
  for (int i = blockIdx.x * blockDim.x + threadIdx.x; i < N; i += stride) {
    int o = offs[i] + bsum[i >> 10];
    offs[i] = o;
    cursor[i] = o;
    int dg = deg[i];
    dis[i] = (dg > 0) ? rsqrtf((float)dg) : 0.f;
  }
}

// Fill CSR with (src, dis[src]) pairs so prop needs no random dis gather.
__global__ void fill_kernel(const int* __restrict__ row, const int* __restrict__ col,
                            int* __restrict__ cursor, int2* __restrict__ csr,
                            const float* __restrict__ dis, int E) {
  int stride = gridDim.x * blockDim.x;
  for (int e = blockIdx.x * blockDim.x + threadIdx.x; e < E; e += stride) {
    int r = row[e];
    int c = col[e];
    int p = atomicAdd(&cursor[c], 1);
    csr[p] = make_int2(r, __float_as_int(dis[r]));
  }
}

// ---------------- Embedding GEMM via MFMA: x = fp16(X) @ fp16(W)^T + b ------
// Block = 256 threads (4 waves), 64 nodes/block. Stage X-tile (64x256) and all
// of W (64x256) as fp16 in LDS (padded stride 264 to balance banks). Each wave
// computes 16 nodes x 64 dims with 4 accumulators over 8 k-steps of 32.
// C layout: col = lane&15, row = (lane>>4)*4 + reg  [m89-verified].
#define LDS_STRIDE 264

__global__ void __launch_bounds__(256) embed_kernel(
    const float* __restrict__ X, const float* __restrict__ W,
    const float* __restrict__ bias, __half* __restrict__ x_out, int N) {
  __shared__ _Float16 Xl[64 * LDS_STRIDE];
  __shared__ _Float16 Wl[64 * LDS_STRIDE];
  const int t = threadIdx.x;
  const int base = blockIdx.x * 64;

  // Stage W and X tile: 16 passes x 256 threads x float4.
#pragma unroll 4
  for (int p = 0; p < 16; ++p) {
    int flat = p * 256 + t;
    int row = flat >> 6;        // 0..63
    int col4 = flat & 63;       // float4 index within row of 256
    float4 wv = *reinterpret_cast<const float4*>(W + (size_t)row * NFEAT + col4 * 4);
    __half2 w01 = __floats2half2_rn(wv.x, wv.y);
    __half2 w23 = __floats2half2_rn(wv.z, wv.w);
    uint2 wp = make_uint2(*reinterpret_cast<unsigned int*>(&w01),
                          *reinterpret_cast<unsigned int*>(&w23));
    *reinterpret_cast<uint2*>(&Wl[row * LDS_STRIDE + col4 * 4]) = wp;

    int xrow = base + row;
    int xr = (xrow < N) ? xrow : (N - 1);
    float4 xv = *reinterpret_cast<const float4*>(X + (size_t)xr * NFEAT + col4 * 4);
    __half2 x01 = __floats2half2_rn(xv.x, xv.y);
    __half2 x23 = __floats2half2_rn(xv.z, xv.w);
    uint2 xp = make_uint2(*reinterpret_cast<unsigned int*>(&x01),
                          *reinterpret_cast<unsigned int*>(&x23));
    *reinterpret_cast<uint2*>(&Xl[row * LDS_STRIDE + col4 * 4]) = xp;
  }
  __syncthreads();

  const int lane = t & 63;
  const int w = t >> 6;        // wave id: nodes base + w*16 .. +15
  const int r = lane & 15;
  const int g = lane >> 4;

  f32x4 acc[4];
#pragma unroll
  for (int n = 0; n < 4; ++n) acc[n] = (f32x4){0.f, 0.f, 0.f, 0.f};

#pragma unroll
  for (int s = 0; s < 8; ++s) {
    f16x8 a = *reinterpret_cast<const f16x8*>(&Xl[(w * 16 + r) * LDS_STRIDE + s * 32 + 8 * g]);
#pragma unroll
    for (int n = 0; n < 4; ++n) {
      f16x8 bfr = *reinterpret_cast<const f16x8*>(&Wl[(n * 16 + r) * LDS_STRIDE + s * 32 + 8 * g]);
      acc[n] = __builtin_amdgcn_mfma_f32_16x16x32_f16(a, bfr, acc[n], 0, 0, 0);
    }
  }

  // Epilogue: node = base + w*16 + g*4 + reg, dim = n*16 + r.
  float bv[4];
#pragma unroll
  for (int n = 0; n < 4; ++n) bv[n] = bias[n * 16 + r];
#pragma unroll
  for (int reg = 0; reg < 4; ++reg) {
    int node = base + w * 16 + g * 4 + reg;
    if (node < N) {
#pragma unroll
      for (int n = 0; n < 4; ++n) {
        float val = acc[n][reg] + bv[n];
        x_out[(size_t)node * EDIM + n * 16 + r] = __float2half(val);
      }
    }
  }
}

// ---------------- Propagation (gather form, no atomics) ----------------
// Wave per destination node; FOUR 16-lane quarters each process a contiguous
// slice of the dst's edge list. Lane owns 4 dims via one uint2 (8B) load, so
// one load instruction covers 4 edge-rows; unroll-4 => 16 row-gathers in
// flight per wave. Out-of-range unroll slots use the zero-weight trick
// (gather row 0, weight 0). f32 accumulate; cross-quarter shfl_xor(16,32).
// out_acc fp16; layer==0 initializes it; last layer skips dead x_out store.

__global__ void prop_kernel(const __half* __restrict__ x_in, __half* __restrict__ x_out,
                            __half* __restrict__ out_acc, const int* __restrict__ offs,
                            const int* __restrict__ deg, const int2* __restrict__ csr,
                            const float* __restrict__ dis, const float* __restrict__ alpha,
                            int layer, int last, int N) {
  const int lane = threadIdx.x & 63;
  const int qt = lane >> 4;    // quarter 0..3: which edge-slice
  const int s16 = lane & 15;   // dims 4*s16 .. 4*s16+3
  int wid = (blockIdx.x * blockDim.x + threadIdx.x) >> 6;
  int nw = (gridDim.x * blockDim.x) >> 6;
  float al = alpha[layer + 1];
  float a0 = alpha[0];
  const int2 z2 = make_int2(0, 0);
  for (int c = wid; c < N; c += nw) {
    int start = offs[c];
    int cnt = deg[c];
    int cntQ = (cnt + 3) >> 2;
    int myCnt = min(cntQ, max(0, cnt - qt * cntQ));
    int myStart = start + qt * cntQ;
    float ax = 0.f, ay = 0.f, az = 0.f, aw = 0.f;
    for (int j = 0; j < cntQ; j += 4) {
      int2 e0 = (j + 0 < myCnt) ? csr[myStart + j + 0] : z2;
      int2 e1 = (j + 1 < myCnt) ? csr[myStart + j + 1] : z2;
      int2 e2 = (j + 2 < myCnt) ? csr[myStart + j + 2] : z2;
      int2 e3 = (j + 3 < myCnt) ? csr[myStart + j + 3] : z2;
      uint2 v0 = *(reinterpret_cast<const uint2*>(x_in + (size_t)e0.x * EDIM) + s16);
      uint2 v1 = *(reinterpret_cast<const uint2*>(x_in + (size_t)e1.x * EDIM) + s16);
      uint2 v2 = *(reinterpret_cast<const uint2*>(x_in + (size_t)e2.x * EDIM) + s16);
      uint2 v3 = *(reinterpret_cast<const uint2*>(x_in + (size_t)e3.x * EDIM) + s16);
      float w0 = __int_as_float(e0.y), w1 = __int_as_float(e1.y);
      float w2 = __int_as_float(e2.y), w3 = __int_as_float(e3.y);
      float2 lo, hi;
      lo = __half22float2(*reinterpret_cast<const __half2*>(&v0.x));
      hi = __half22float2(*reinterpret_cast<const __half2*>(&v0.y));
      ax = fmaf(w0, lo.x, ax); ay = fmaf(w0, lo.y, ay);
      az = fmaf(w0, hi.x, az); aw = fmaf(w0, hi.y, aw);
      lo = __half22float2(*reinterpret_cast<const __half2*>(&v1.x));
      hi = __half22float2(*reinterpret_cast<const __half2*>(&v1.y));
      ax = fmaf(w1, lo.x, ax); ay = fmaf(w1, lo.y, ay);
      az = fmaf(w1, hi.x, az); aw = fmaf(w1, hi.y, aw);
      lo = __half22float2(*reinterpret_cast<const __half2*>(&v2.x));
      hi = __half22float2(*reinterpret_cast<const __half2*>(&v2.y));
      ax = fmaf(w2, lo.x, ax); ay = fmaf(w2, lo.y, ay);
      az = fmaf(w2, hi.x, az); aw = fmaf(w2, hi.y, aw);
      lo = __half22float2(*reinterpret_cast<const __half2*>(&v3.x));
      hi = __half22float2(*reinterpret_cast<const __half2*>(&v3.y));
      ax = fmaf(w3, lo.x, ax); ay = fmaf(w3, lo.y, ay);
      az = fmaf(w3, hi.x, az); aw = fmaf(w3, hi.y, aw);
    }
    ax += __shfl_xor(ax, 16); ax += __shfl_xor(ax, 32);
    ay += __shfl_xor(ay, 16); ay += __shfl_xor(ay, 32);
    az += __shfl_xor(az, 16); az += __shfl_xor(az, 32);
    aw += __shfl_xor(aw, 16); aw += __shfl_xor(aw, 32);
    if (qt == 0) {
      float dc = dis[c];
      float vx = ax * dc, vy = ay * dc, vz = az * dc, vw = aw * dc;
      size_t base = (size_t)c * EDIM + s16 * 4;
      if (!last) {
        __half2 p01 = __floats2half2_rn(vx, vy);
        __half2 p23 = __floats2half2_rn(vz, vw);
        uint2 pk = make_uint2(*reinterpret_cast<unsigned int*>(&p01),
                              *reinterpret_cast<unsigned int*>(&p23));
        *reinterpret_cast<uint2*>(x_out + base) = pk;
      }
      float ox, oy, oz, ow;
      if (layer == 0) {
        uint2 xf = *reinterpret_cast<const uint2*>(x_in + base);
        float2 xlo = __half22float2(*reinterpret_cast<const __half2*>(&xf.x));
        float2 xhi = __half22float2(*reinterpret_cast<const __half2*>(&xf.y));
        ox = fmaf(a0, xlo.x, al * vx); oy = fmaf(a0, xlo.y, al * vy);
        oz = fmaf(a0, xhi.x, al * vz); ow = fmaf(a0, xhi.y, al * vw);
      } else {
        uint2 pv = *reinterpret_cast<const uint2*>(out_acc + base);
        float2 plo = __half22float2(*reinterpret_cast<const __half2*>(&pv.x));
        float2 phi = __half22float2(*reinterpret_cast<const __half2*>(&pv.y));
        ox = fmaf(al, vx, plo.x); oy = fmaf(al, vy, plo.y);
        oz = fmaf(al, vz, phi.x); ow = fmaf(al, vw, phi.y);
      }
      __half2 o01 = __floats2half2_rn(ox, oy);
      __half2 o23 = __floats2half2_rn(oz, ow);
      uint2 ok = make_uint2(*reinterpret_cast<unsigned int*>(&o01),
                            *reinterpret_cast<unsigned int*>(&o23));
      *reinterpret_cast<uint2*>(out_acc + base) = ok;
    }
  }
}

// ---------------- Output gather ----------------
// 32B of output per thread-iteration: one uint4 (8 fp16) gather -> two
// nontemporal float4 stores. Row = [src(64) | dst(64)].

__global__ void gatherout_kernel(const __half* __restrict__ oacc, const int* __restrict__ lsrc,
                                 const int* __restrict__ ldst, float* __restrict__ out, int L) {
  int total = L * 16;
  int stride = gridDim.x * blockDim.x;
  for (int i = blockIdx.x * blockDim.x + threadIdx.x; i < total; i += stride) {
    int l = i >> 4;
    int q = i & 15;            // 16 chunks of 8 floats per 128-float row
    int node = (q < 8) ? lsrc[l] : ldst[l];
    int qq = q & 7;            // 8-float chunk within the 64-dim half
    uint4 h = *reinterpret_cast<const uint4*>(oacc + (size_t)node * EDIM + qq * 8);
    float2 a = __half22float2(*reinterpret_cast<const __half2*>(&h.x));
    float2 b = __half22float2(*reinterpret_cast<const __half2*>(&h.y));
    float2 cc = __half22float2(*reinterpret_cast<const __half2*>(&h.z));
    float2 d = __half22float2(*reinterpret_cast<const __half2*>(&h.w));
    f4_t v0 = {a.x, a.y, b.x, b.y};
    f4_t v1 = {cc.x, cc.y, d.x, d.y};
    float* dst = out + (size_t)l * 128 + q * 8;
    __builtin_nontemporal_store(v0, reinterpret_cast<f4_t*>(dst));
    __builtin_nontemporal_store(v1, reinterpret_cast<f4_t*>(dst + 4));
  }
}

// ---------------- Launch ----------------

extern "C" void kernel_launch(void* const* d_in, const int* in_sizes, int n_in,
                              void* d_out, int out_size, void* d_ws, size_t ws_size,
                              hipStream_t stream) {
  const float* X = (const float*)d_in[0];
  const float* W = (const float*)d_in[1];
  const float* b = (const float*)d_in[2];
  const float* alpha = (const float*)d_in[3];
  const int* ei = (const int*)d_in[4];
  const int* eli = (const int*)d_in[5];
  int N = in_sizes[0] / NFEAT;
  int E = in_sizes[4] / 2;
  int L = in_sizes[5] / 2;
  const int* rowp = ei;
  const int* colp = ei + E;
  const int* lsrc = eli;
  const int* ldst = eli + L;
  float* out = (float*)d_out;

  char* ws = (char*)d_ws;
  size_t off = 0;
  auto alloc = [&](size_t bytes) -> void* {
    void* p = ws + off;
    off += (bytes + 255) & ~(size_t)255;
    return p;
  };
  int* deg = (int*)alloc((size_t)N * 4);
  int* offs = (int*)alloc((size_t)N * 4);
  int* cursor = (int*)alloc((size_t)N * 4);
  int* bsum = (int*)alloc(1024);
  float* dis = (float*)alloc((size_t)N * 4);
  int2* csr = (int2*)alloc((size_t)(E + 16) * 8);
  __half* xa = (__half*)alloc((size_t)N * EDIM * 2);
  __half* xb = (__half*)alloc((size_t)N * EDIM * 2);
  __half* oacc = (__half*)alloc((size_t)N * EDIM * 2);
  (void)ws_size;
  (void)n_in;
  (void)out_size;

  (void)hipMemsetAsync(deg, 0, (size_t)N * 4, stream);
  hist_kernel<<<2048, 256, 0, stream>>>(colp, deg, E);
  int nb = (N + 1023) / 1024;  // 98 for N=100000; scan2 requires nb <= 256
  scan1_kernel<<<nb, 256, 0, stream>>>(deg, offs, bsum, N);
  scan2_kernel<<<1, 256, 0, stream>>>(bsum, nb);
  finalize_kernel<<<(N + 255) / 256, 256, 0, stream>>>(offs, cursor, deg, dis, bsum, N);
  fill_kernel<<<2048, 256, 0, stream>>>(rowp, colp, cursor, csr, dis, E);
  embed_kernel<<<(N + 63) / 64, 256, 0, stream>>>(X, W, b, xa, N);
  prop_kernel<<<2048, 256, 0, stream>>>(xa, xb, oacc, offs, deg, csr, dis, alpha, 0, 0, N);
  prop_kernel<<<2048, 256, 0, stream>>>(xb, xa, oacc, offs, deg, csr, dis, alpha, 1, 0, N);
  prop_kernel<<<2048, 256, 0, stream>>>(xa, xb, oacc, offs, deg, csr, dis, alpha, 2, 1, N);
  gatherout_kernel<<<4096, 256, 0, stream>>>(oacc, lsrc, ldst, out, L);
}